// Round 1
// baseline (245.165 us; speedup 1.0000x reference)
//
#include <hip/hip_runtime.h>

constexpr int Bn = 4096;
constexpr int Dn = 256;
constexpr int Sn = 256;
constexpr int Kw = 513;   // 2*D + 1

// ---------------------------------------------------------------------------
// Kernel 1: user_item_feature[b,d] = bias[d] + sum_k uf_cat[b,k] * W[d,k]
// grid = Bn/ROWS blocks, 256 threads. uf rows + W k-chunk staged in LDS so
// all global traffic is coalesced; W read Bn/ROWS times total (L2-resident).
// Output written into d_out's feature region (same shape), consumed and then
// overwritten by kernel 2.
// ---------------------------------------------------------------------------
constexpr int ROWS = 8;
constexpr int KCH  = 32;

__global__ __launch_bounds__(256) void feat_kernel(
    const float* __restrict__ uf, const float* __restrict__ priv,
    const float* __restrict__ W,  const float* __restrict__ bias,
    float* __restrict__ fout) {
  __shared__ float uf_s[ROWS][Kw];
  __shared__ float w_s[Dn][KCH + 1];
  const int t  = threadIdx.x;
  const int b0 = blockIdx.x * ROWS;

  for (int i = t; i < ROWS * Kw; i += 256) {
    int r = i / Kw, k = i - r * Kw;
    uf_s[r][k] = (k < 2 * Dn) ? uf[(size_t)(b0 + r) * (2 * Dn) + k]
                              : priv[b0 + r];
  }

  float acc[ROWS];
  const float bd = bias[t];
#pragma unroll
  for (int r = 0; r < ROWS; ++r) acc[r] = bd;

  for (int k0 = 0; k0 < Kw; k0 += KCH) {
    const int kcnt = min(KCH, Kw - k0);
    __syncthreads();  // also covers initial uf_s fill on first iteration
    for (int i = t; i < Dn * kcnt; i += 256) {
      int d = i / kcnt, kk = i - d * kcnt;
      w_s[d][kk] = W[(size_t)d * Kw + k0 + kk];
    }
    __syncthreads();
    for (int kk = 0; kk < kcnt; ++kk) {
      float w = w_s[t][kk];
#pragma unroll
      for (int r = 0; r < ROWS; ++r) acc[r] += uf_s[r][k0 + kk] * w;
    }
  }
#pragma unroll
  for (int r = 0; r < ROWS; ++r) fout[(size_t)(b0 + r) * Dn + t] = acc[r];
}

// ---------------------------------------------------------------------------
// Kernel 2: per-b scores -> softmax -> weighted item index + weighted feature
// grid = Bn blocks, 256 threads (4 waves). Wave w scores s = w*64 + i via a
// coalesced float4 load (lane l covers dims 4l..4l+3) + shuffle reduce.
// Softmax in LDS; second einsum runs only over compacted s with p >= 1e-7
// (deterministic ballot/prefix compaction).
// ---------------------------------------------------------------------------
__global__ __launch_bounds__(256) void main_kernel(
    const int* __restrict__ need_replace,
    const int* __restrict__ user_sample_items,
    const float* __restrict__ all_items,
    float* __restrict__ out_items,   // d_out + 0, Bn floats
    float* __restrict__ feat_io,     // d_out + Bn: f in, feature out
    float* __restrict__ out_scalars) // d_out + Bn + Bn*Dn, 2 floats
{
  __shared__ __align__(16) float f_s[Dn];
  __shared__ int   items_s[Sn];
  __shared__ float sc_s[Sn];
  __shared__ float red_s[8];
  __shared__ int   sel_idx[Sn];
  __shared__ float sel_p[Sn];
  __shared__ int   warp_cnt[4];

  const int b    = blockIdx.x;
  const int t    = threadIdx.x;
  const int lane = t & 63;
  const int w    = t >> 6;

  const int uid = need_replace[b * 2];
  items_s[t] = user_sample_items[(size_t)uid * Sn + t];
  f_s[t]     = feat_io[(size_t)b * Dn + t];
  __syncthreads();

  // ---- pass 1: scores ----
  const float4 fr = *(const float4*)&f_s[lane * 4];
  for (int i = 0; i < 64; ++i) {
    const int s    = w * 64 + i;
    const int item = items_s[s];
    const float4 e = *(const float4*)&all_items[(size_t)item * Dn + lane * 4];
    float p = fr.x * e.x + fr.y * e.y + fr.z * e.z + fr.w * e.w;
#pragma unroll
    for (int off = 32; off; off >>= 1) p += __shfl_xor(p, off);
    if (lane == 0) sc_s[s] = p;
  }
  __syncthreads();

  // ---- softmax over S ----
  const float v = sc_s[t];
  float m = v;
#pragma unroll
  for (int off = 32; off; off >>= 1) m = fmaxf(m, __shfl_xor(m, off));
  if (lane == 0) red_s[w] = m;
  __syncthreads();
  m = fmaxf(fmaxf(red_s[0], red_s[1]), fmaxf(red_s[2], red_s[3]));

  const float e = expf(v - m);
  float ssum = e;
#pragma unroll
  for (int off = 32; off; off >>= 1) ssum += __shfl_xor(ssum, off);
  if (lane == 0) red_s[4 + w] = ssum;
  __syncthreads();
  const float tot = red_s[4] + red_s[5] + red_s[6] + red_s[7];
  const float p = e / tot;

  // ---- weighted item index (exact, all s) ----
  float ri = p * (float)items_s[t];
#pragma unroll
  for (int off = 32; off; off >>= 1) ri += __shfl_xor(ri, off);
  // red_s[0..3] reads above all happened before this barrier-free write is
  // observed; publish after reduce:
  if (lane == 0) red_s[w] = ri;

  // ---- deterministic compaction of significant p ----
  const bool flag = (p >= 1e-7f);
  const unsigned long long mask = __ballot(flag);
  const int wc     = __popcll(mask);
  const int prefix = __popcll(mask & ((1ull << lane) - 1ull));
  if (lane == 0) warp_cnt[w] = wc;
  __syncthreads();

  if (t == 0) {
    const float tot_ri = red_s[0] + red_s[1] + red_s[2] + red_s[3];
    out_items[b] = (float)(int)tot_ri;  // astype(int32) truncation
  }
  int off0 = 0;
  for (int i = 0; i < w; ++i) off0 += warp_cnt[i];
  const int nsel = warp_cnt[0] + warp_cnt[1] + warp_cnt[2] + warp_cnt[3];
  if (flag) {
    sel_idx[off0 + prefix] = items_s[t];
    sel_p[off0 + prefix]   = p;
  }
  __syncthreads();

  // ---- pass 2: weighted feature over compacted s ----
  float acc = 0.f;
  for (int i = 0; i < nsel; ++i) {
    acc += sel_p[i] * all_items[(size_t)sel_idx[i] * Dn + t];
  }
  feat_io[(size_t)b * Dn + t] = acc;

  if (b == 0 && t < 2) out_scalars[t] = 0.f;
}

extern "C" void kernel_launch(void* const* d_in, const int* in_sizes, int n_in,
                              void* d_out, int out_size, void* d_ws, size_t ws_size,
                              hipStream_t stream) {
  const int*   need_replace      = (const int*)d_in[0];
  const float* union_feature     = (const float*)d_in[1];
  const float* all_items         = (const float*)d_in[2];
  const float* privacy_settings  = (const float*)d_in[3];
  const int*   user_sample_items = (const int*)d_in[4];
  const float* W                 = (const float*)d_in[5];
  const float* bias              = (const float*)d_in[6];

  float* out        = (float*)d_out;
  float* out_items  = out;                 // Bn
  float* feat_io    = out + Bn;            // Bn*Dn (scratch f, then feature)
  float* out_scal   = out + Bn + (size_t)Bn * Dn;  // 2 scalars

  feat_kernel<<<Bn / ROWS, 256, 0, stream>>>(union_feature, privacy_settings,
                                             W, bias, feat_io);
  main_kernel<<<Bn, 256, 0, stream>>>(need_replace, user_sample_items,
                                      all_items, out_items, feat_io, out_scal);
}